// Round 5
// baseline (495.557 us; speedup 1.0000x reference)
//
#include <hip/hip_runtime.h>
#include <math.h>

// Problem constants (from reference)
#define BB 4
#define NN 1000
#define TT 12
#define DD 64
#define HIDN 128
#define EFN 64
#define EE 64000
#define BN (BB*NN)        // 4000 segments
#define ROWS (BN*TT)      // 48000 node-time rows
#define TD (TT*DD)        // 768 elements per edge/node row-block
#define TD4 (TD/4)        // 192 float4 per row-block
#define STEPF 0.1f
#define MAXSEG 28         // LDS-resident edges per sender segment (2 blocks/CU)
#define ELDS 40           // staged edge ids per block

typedef _Float16 f16x8 __attribute__((ext_vector_type(8)));   // 8 x f16 (4 VGPR)
typedef float f32x4 __attribute__((ext_vector_type(4)));      // MFMA acc

__device__ __forceinline__ unsigned short f2h(float x) {
    _Float16 h = (_Float16)x;                 // v_cvt_f16_f32 (RNE)
    return __builtin_bit_cast(unsigned short, h);
}
__device__ __forceinline__ float h2f(unsigned short u) {
    return (float)__builtin_bit_cast(_Float16, u);
}

// ---------------------------------------------------------------------------
// CSR build helpers
// ---------------------------------------------------------------------------
__global__ __launch_bounds__(256) void k_zero(int* __restrict__ p, int n) {
    int i = blockIdx.x * 256 + threadIdx.x;
    if (i < n) p[i] = 0;
}

__global__ __launch_bounds__(256) void k_count(const int* __restrict__ bi,
                                               const int* __restrict__ si,
                                               const int* __restrict__ ri,
                                               int* __restrict__ cnt_s,
                                               int* __restrict__ cnt_r) {
    int e = blockIdx.x * 256 + threadIdx.x;
    if (e < EE) {
        int b = bi[e];
        atomicAdd(&cnt_s[b * NN + si[e]], 1);
        atomicAdd(&cnt_r[b * NN + ri[e]], 1);
    }
}

__global__ __launch_bounds__(256) void k_scan(const int* __restrict__ cnt_s,
                                              const int* __restrict__ cnt_r,
                                              int* __restrict__ rp_s, int* __restrict__ rp_r,
                                              int* __restrict__ cur_s, int* __restrict__ cur_r) {
    const int* cnt = blockIdx.x ? cnt_r : cnt_s;
    int* rp  = blockIdx.x ? rp_r  : rp_s;
    int* cur = blockIdx.x ? cur_r : cur_s;
    __shared__ int part[256];
    int tid = threadIdx.x;
    const int chunk = 16;
    int bgn = tid * chunk;
    int end = min(bgn + chunk, BN);
    int s = 0;
    for (int i = bgn; i < end; ++i) s += cnt[i];
    part[tid] = s;
    __syncthreads();
    for (int off = 1; off < 256; off <<= 1) {
        int v = part[tid];
        if (tid >= off) v += part[tid - off];
        __syncthreads();
        part[tid] = v;
        __syncthreads();
    }
    int run = tid ? part[tid - 1] : 0;
    for (int i = bgn; i < end; ++i) { rp[i] = run; cur[i] = run; run += cnt[i]; }
    if (tid == 255) rp[BN] = part[255];
}

__global__ __launch_bounds__(256) void k_fill(const int* __restrict__ bi,
                                              const int* __restrict__ si,
                                              const int* __restrict__ ri,
                                              int* __restrict__ cur_s, int* __restrict__ cur_r,
                                              int* __restrict__ el_s, int* __restrict__ el_r) {
    int e = blockIdx.x * 256 + threadIdx.x;
    if (e < EE) {
        int b = bi[e];
        int ps = atomicAdd(&cur_s[b * NN + si[e]], 1);
        el_s[ps] = e;
        int pr = atomicAdd(&cur_r[b * NN + ri[e]], 1);
        el_r[pr] = e;
    }
}

// ---------------------------------------------------------------------------
// Weight prep: repack all four weight matrices into f16 MFMA B-fragment order
// for 16x16x32: frag[kt][nt][lane][j] = W[kt*32 + (lane>>4)*8 + j][nt*16 + (lane&15)]
//   W3f: A3_w [128,64]  (4 kt x 4 nt) -> 8192
//   W4f: A4_w [64,64]   (2 kt x 4 nt) -> 4096
//   W1f: A1_w [64,128]  (2 kt x 8 nt) -> 8192
//   W2f: A2_w [64,128]  (2 kt x 8 nt) -> 8192
// ---------------------------------------------------------------------------
__global__ __launch_bounds__(256) void k_prep_w(const float* __restrict__ A3_w,
                                                const float* __restrict__ A4_w,
                                                const float* __restrict__ A1_w,
                                                const float* __restrict__ A2_w,
                                                unsigned short* __restrict__ W3f,
                                                unsigned short* __restrict__ W4f,
                                                unsigned short* __restrict__ W1f,
                                                unsigned short* __restrict__ W2f) {
    int i = blockIdx.x * 256 + threadIdx.x;    // 0 .. 28671
    if (i < 8192) {
        int j = i & 7, lane = (i >> 3) & 63, nt = (i >> 9) & 3, kt = i >> 11;
        int k = kt * 32 + (lane >> 4) * 8 + j;
        int n = nt * 16 + (lane & 15);
        W3f[i] = f2h(A3_w[k * 64 + n]);
    } else if (i < 12288) {
        int ii = i - 8192;
        int j = ii & 7, lane = (ii >> 3) & 63, nt = (ii >> 9) & 3, kt = ii >> 11;
        int k = kt * 32 + (lane >> 4) * 8 + j;
        int n = nt * 16 + (lane & 15);
        W4f[ii] = f2h(A4_w[k * 64 + n]);
    } else if (i < 20480) {
        int ii = i - 12288;
        int j = ii & 7, lane = (ii >> 3) & 63, nt = (ii >> 9) & 7, kt = ii >> 12;
        int k = kt * 32 + (lane >> 4) * 8 + j;
        int n = nt * 16 + (lane & 15);
        W1f[ii] = f2h(A1_w[k * 128 + n]);
    } else {
        int ii = i - 20480;
        int j = ii & 7, lane = (ii >> 3) & 63, nt = (ii >> 9) & 7, kt = ii >> 12;
        int k = kt * 32 + (lane >> 4) * 8 + j;
        int n = nt * 16 + (lane & 15);
        W2f[ii] = f2h(A2_w[k * 128 + n]);
    }
}

// ---------------------------------------------------------------------------
// K1 (MFMA): Q1 = x@A1_w + A1_b, Q2 = x@A2_w + A2_b -> f16.
// [48000,64]@[64,128]: each wave does a 16-row x 128-col tile with 16 MFMAs.
// Waves 0,1 -> Q1 rows {rt, rt+16}; waves 2,3 -> Q2 same rows. Memory-bound
// (~37 MB total), replaces the scalar loop (2k VALU/LDS instr per wave).
// ---------------------------------------------------------------------------
__global__ __launch_bounds__(256) void k_node_proj(const float* __restrict__ x,
                                                   const unsigned short* __restrict__ W1f,
                                                   const unsigned short* __restrict__ W2f,
                                                   const float* __restrict__ A1_b,
                                                   const float* __restrict__ A2_b,
                                                   unsigned short* __restrict__ Q1,
                                                   unsigned short* __restrict__ Q2) {
    int tid  = threadIdx.x;
    int lane = tid & 63;
    int wvv  = tid >> 6;            // 0..3
    int mat  = wvv >> 1;            // 0 -> Q1, 1 -> Q2
    int rt   = blockIdx.x * 32 + (wvv & 1) * 16;
    int quad = lane >> 4;
    int m    = lane & 15;

    const unsigned short* Wf = mat ? W2f : W1f;
    const float* bias = mat ? A2_b : A1_b;
    unsigned short* Qo = mat ? Q2 : Q1;

    f16x8 wf[2][8];
#pragma unroll
    for (int kt = 0; kt < 2; ++kt)
#pragma unroll
        for (int nt = 0; nt < 8; ++nt)
            wf[kt][nt] = *(const f16x8*)(const void*)&Wf[((kt * 8 + nt) * 64 + lane) * 8];

    float bb[8];
#pragma unroll
    for (int nt = 0; nt < 8; ++nt) bb[nt] = bias[nt * 16 + m];

    // A fragments: af[kt][j] = x[rt+m][kt*32 + quad*8 + j], f32 -> f16
    const float* xr = x + (size_t)(rt + m) * 64;
    f16x8 af[2];
#pragma unroll
    for (int kt = 0; kt < 2; ++kt) {
        float4 u0 = *(const float4*)(xr + kt * 32 + quad * 8);
        float4 u1 = *(const float4*)(xr + kt * 32 + quad * 8 + 4);
        f16x8 a;
        a[0] = (_Float16)u0.x; a[1] = (_Float16)u0.y; a[2] = (_Float16)u0.z; a[3] = (_Float16)u0.w;
        a[4] = (_Float16)u1.x; a[5] = (_Float16)u1.y; a[6] = (_Float16)u1.z; a[7] = (_Float16)u1.w;
        af[kt] = a;
    }

    f32x4 acc[8];
#pragma unroll
    for (int nt = 0; nt < 8; ++nt) {
        f32x4 o = (f32x4){0.f, 0.f, 0.f, 0.f};
        o = __builtin_amdgcn_mfma_f32_16x16x32_f16(af[0], wf[0][nt], o, 0, 0, 0);
        o = __builtin_amdgcn_mfma_f32_16x16x32_f16(af[1], wf[1][nt], o, 0, 0, 0);
        acc[nt] = o;
    }
#pragma unroll
    for (int nt = 0; nt < 8; ++nt)
#pragma unroll
        for (int r = 0; r < 4; ++r)
            Qo[(size_t)(rt + quad * 4 + r) * 128 + nt * 16 + m] = f2h(acc[nt][r] + bb[nt]);
}

// ---------------------------------------------------------------------------
// K2 (f16 MFMA + fused segment softmax): one workgroup per sender segment.
//  - 2-edge ILP interleave: per wave-iter, edges (li, li+4) pipeline as
//    loadA,loadB -> G_A,Z_A,HstoreA -> G_B,Z_B -> HreadA,A4_A -> HstoreB,
//    HreadB,A4_B. B's gather latency hides under A's compute; A's LDS
//    round-trip hides under B's MFMAs. Hs slot reused (program order).
//  - NO occupancy hints (round-3/4 lesson: hints -> 84-reg spill collapse).
//  - 2 blocks/CU (LDS 60.7 KB): keeps receiver-gather L2 hit ~65%.
// ---------------------------------------------------------------------------
__global__ __launch_bounds__(256)
void k_edge_seg(const unsigned short* __restrict__ Q1,
                const unsigned short* __restrict__ Q2,
                const int* __restrict__ ri,
                const int* __restrict__ rp_s,
                const int* __restrict__ el_s,
                const unsigned short* __restrict__ W3f,
                const unsigned short* __restrict__ W4f,
                const float* __restrict__ A4_b,
                float* __restrict__ v) {
    __shared__ unsigned short Vseg[MAXSEG][12][64];   // 43008 B, XOR-swizzled cols
    __shared__ __align__(16) _Float16 Hs[4][16][72];  // 9216 B (pitch 72: 16B-aligned b128 rows)
    __shared__ __align__(16) _Float16 W4s[4096];      // 8192 B, frag-packed A4 weights
    __shared__ int e_lds[ELDS];
    __shared__ int rn_lds[ELDS];

    int seg = blockIdx.x;
    int beg = rp_s[seg], end = rp_s[seg + 1];
    int S = end - beg;
    if (S == 0) return;

    int tid  = threadIdx.x;
    int lane = tid & 63;
    int wv   = tid >> 6;
    int quad = lane >> 4;
    int m    = lane & 15;
    int kbase = quad * 8;
    int b    = seg / NN;           // batch id (seg = b*NN + sender)

    // ---- block-start staging ----
    for (int i = tid; i < 512; i += 256)
        *(f16x8*)&W4s[i * 8] = *(const f16x8*)(const void*)&W4f[i * 8];
    if (tid < ELDS && tid < S) {
        int e = el_s[beg + tid];
        e_lds[tid] = e;
        rn_lds[tid] = b * NN + ri[e];
    }

    // w3 resident in registers (64 VGPR)
    f16x8 w3[4][4];
#pragma unroll
    for (int kt = 0; kt < 4; ++kt)
#pragma unroll
        for (int nt = 0; nt < 4; ++nt)
            w3[kt][nt] = *(const f16x8*)(const void*)&W3f[((kt * 4 + nt) * 64 + lane) * 8];
    float b4[4];
#pragma unroll
    for (int nt = 0; nt < 4; ++nt) b4[nt] = A4_b[nt * 16 + m];

    const f16x8 hz = {0, 0, 0, 0, 0, 0, 0, 0};

    // sender fragments: loop-invariant, persistent in regs (32 VGPR)
    f16x8 s1[4], s2[4];
    if (m < 12) {
        const unsigned short* p1 = Q1 + (size_t)seg * (TT * HIDN) + m * 128 + kbase;
        const unsigned short* p2 = Q2 + (size_t)seg * (TT * HIDN) + m * 128 + kbase;
#pragma unroll
        for (int kt = 0; kt < 4; ++kt) {
            s1[kt] = *(const f16x8*)(const void*)(p1 + kt * 32);
            s2[kt] = *(const f16x8*)(const void*)(p2 + kt * 32);
        }
    } else {
#pragma unroll
        for (int kt = 0; kt < 4; ++kt) { s1[kt] = hz; s2[kt] = hz; }
    }

    __syncthreads();

    auto build_g = [&](const f16x8* r1, const f16x8* r2, f16x8* g) {
        if (m < 12) {
#pragma unroll
            for (int kt = 0; kt < 4; ++kt) {
                f16x8 a = s1[kt] + r2[kt];                // v_pk_add_f16
                f16x8 c = r1[kt] + s2[kt];
                g[kt] = __builtin_elementwise_max(a, hz)  // v_pk_max_f16
                      - __builtin_elementwise_max(c, hz);
            }
        } else {
#pragma unroll
            for (int kt = 0; kt < 4; ++kt) g[kt] = hz;
        }
    };
    auto zmfma = [&](const f16x8* g, f32x4* acc) {
#pragma unroll
        for (int nt = 0; nt < 4; ++nt) acc[nt] = (f32x4){0.f, 0.f, 0.f, 0.f};
#pragma unroll
        for (int kt = 0; kt < 4; ++kt)
#pragma unroll
            for (int nt = 0; nt < 4; ++nt)
                acc[nt] = __builtin_amdgcn_mfma_f32_16x16x32_f16(g[kt], w3[kt][nt], acc[nt], 0, 0, 0);
    };
    auto h_store = [&](const f32x4* acc) {
#pragma unroll
        for (int nt = 0; nt < 4; ++nt)
#pragma unroll
            for (int r = 0; r < 4; ++r)
                Hs[wv][quad * 4 + r][nt * 16 + m] = (_Float16)fmaxf(acc[nt][r], 0.f);
    };
    auto finish = [&](int lx, int ex) {                   // H read -> A4 -> store
        const _Float16* hp = &Hs[wv][m][kbase];
        f16x8 hf0 = *(const f16x8*)hp;                    // ds_read_b128
        f16x8 hf1 = *(const f16x8*)(hp + 32);
#pragma unroll
        for (int nt = 0; nt < 4; ++nt) {
            f32x4 o = (f32x4){b4[nt], b4[nt], b4[nt], b4[nt]};
            o = __builtin_amdgcn_mfma_f32_16x16x32_f16(hf0, *(const f16x8*)&W4s[(nt * 64 + lane) * 8], o, 0, 0, 0);
            o = __builtin_amdgcn_mfma_f32_16x16x32_f16(hf1, *(const f16x8*)&W4s[((4 + nt) * 64 + lane) * 8], o, 0, 0, 0);
            if (quad < 3) {
                if (lx < MAXSEG) {
                    int cc = ((nt ^ quad) << 4) | m;      // swizzled column
#pragma unroll
                    for (int r = 0; r < 4; ++r)
                        Vseg[lx][quad * 4 + r][cc] = f2h(o[r]);
                } else {            // rare overflow: spill fp32 v_pre to global
                    size_t ebase = (size_t)ex * TD;
#pragma unroll
                    for (int r = 0; r < 4; ++r)
                        v[ebase + (quad * 4 + r) * 64 + nt * 16 + m] = o[r];
                }
            }
        }
    };

    // ---- edge loop: two edges in flight per wave-iter ----
    int li = wv;
    for (; li + 4 < S; li += 8) {
        int liB = li + 4;
        int eA, rnA, eB, rnB;
        if (li  < ELDS) { eA = e_lds[li];  rnA = rn_lds[li];  }
        else            { eA = el_s[beg + li];  rnA = b * NN + ri[eA]; }
        if (liB < ELDS) { eB = e_lds[liB]; rnB = rn_lds[liB]; }
        else            { eB = el_s[beg + liB]; rnB = b * NN + ri[eB]; }

        f16x8 ra1[4], ra2[4], rb1[4], rb2[4];
        if (m < 12) {
            const unsigned short* pa1 = Q1 + (size_t)rnA * (TT * HIDN) + m * 128 + kbase;
            const unsigned short* pa2 = Q2 + (size_t)rnA * (TT * HIDN) + m * 128 + kbase;
            const unsigned short* pb1 = Q1 + (size_t)rnB * (TT * HIDN) + m * 128 + kbase;
            const unsigned short* pb2 = Q2 + (size_t)rnB * (TT * HIDN) + m * 128 + kbase;
#pragma unroll
            for (int kt = 0; kt < 4; ++kt) {
                ra1[kt] = *(const f16x8*)(const void*)(pa1 + kt * 32);
                ra2[kt] = *(const f16x8*)(const void*)(pa2 + kt * 32);
                rb1[kt] = *(const f16x8*)(const void*)(pb1 + kt * 32);
                rb2[kt] = *(const f16x8*)(const void*)(pb2 + kt * 32);
            }
        }

        f16x8 gA[4];  build_g(ra1, ra2, gA);
        f32x4 accA[4]; zmfma(gA, accA);
        h_store(accA);

        f16x8 gB[4];  build_g(rb1, rb2, gB);
        f32x4 accB[4]; zmfma(gB, accB);

        finish(li, eA);
        h_store(accB);
        finish(liB, eB);
    }
    if (li < S) {                       // tail: single edge
        int e, rn;
        if (li < ELDS) { e = e_lds[li]; rn = rn_lds[li]; }
        else           { e = el_s[beg + li]; rn = b * NN + ri[e]; }
        f16x8 r1[4], r2[4];
        if (m < 12) {
            const unsigned short* pr1 = Q1 + (size_t)rn * (TT * HIDN) + m * 128 + kbase;
            const unsigned short* pr2 = Q2 + (size_t)rn * (TT * HIDN) + m * 128 + kbase;
#pragma unroll
            for (int kt = 0; kt < 4; ++kt) {
                r1[kt] = *(const f16x8*)(const void*)(pr1 + kt * 32);
                r2[kt] = *(const f16x8*)(const void*)(pr2 + kt * 32);
            }
        }
        f16x8 g[4];  build_g(r1, r2, g);
        f32x4 acc[4]; zmfma(g, acc);
        h_store(acc);
        finish(li, e);
    }
    __syncthreads();

    // ---- fused segment softmax: thread owns j = tid, tid+256, tid+512 ----
    int d  = tid & 63;
    int tb = tid >> 6;          // row for jj is tb + 4*jj; row>>2 == jj (tb<4)
    int nL = min(S, MAXSEG);
    int dd[3];
#pragma unroll
    for (int jj = 0; jj < 3; ++jj) dd[jj] = d ^ (jj << 4);   // un-swizzle

    float mj[3] = {-1e30f, -1e30f, -1e30f};
    for (int i = 0; i < nL; ++i) {
#pragma unroll
        for (int jj = 0; jj < 3; ++jj)
            mj[jj] = fmaxf(mj[jj], h2f(Vseg[i][tb + 4 * jj][dd[jj]]));
    }
    for (int i = MAXSEG; i < S; ++i) {
        int e = (i < ELDS) ? e_lds[i] : el_s[beg + i];
        size_t ebase = (size_t)e * TD;
#pragma unroll
        for (int jj = 0; jj < 3; ++jj)
            mj[jj] = fmaxf(mj[jj], v[ebase + (tb + 4 * jj) * 64 + d]);
    }

    float sj[3] = {0.f, 0.f, 0.f};
    for (int i = 0; i < nL; ++i) {
#pragma unroll
        for (int jj = 0; jj < 3; ++jj)
            sj[jj] += __expf(h2f(Vseg[i][tb + 4 * jj][dd[jj]]) - mj[jj]);
    }
    for (int i = MAXSEG; i < S; ++i) {
        int e = (i < ELDS) ? e_lds[i] : el_s[beg + i];
        size_t ebase = (size_t)e * TD;
#pragma unroll
        for (int jj = 0; jj < 3; ++jj)
            sj[jj] += __expf(v[ebase + (tb + 4 * jj) * 64 + d] - mj[jj]);
    }

    float inv[3];
#pragma unroll
    for (int jj = 0; jj < 3; ++jj) inv[jj] = 1.f / (sj[jj] + 1e-12f);

    for (int i = 0; i < nL; ++i) {
        int e = (i < ELDS) ? e_lds[i] : el_s[beg + i];
        size_t ebase = (size_t)e * TD;
#pragma unroll
        for (int jj = 0; jj < 3; ++jj)
            v[ebase + (tb + 4 * jj) * 64 + d] =
                __expf(h2f(Vseg[i][tb + 4 * jj][dd[jj]]) - mj[jj]) * inv[jj];
    }
    for (int i = MAXSEG; i < S; ++i) {
        int e = (i < ELDS) ? e_lds[i] : el_s[beg + i];
        size_t ebase = (size_t)e * TD;
#pragma unroll
        for (int jj = 0; jj < 3; ++jj) {
            size_t a = ebase + (tb + 4 * jj) * 64 + d;
            v[a] = __expf(v[a] - mj[jj]) * inv[jj];
        }
    }
}

// ---------------------------------------------------------------------------
// K4: per-node inbound aggregation + state update. 192 threads x float4.
// Edge loop unrolled x4: 8 independent loads in flight per iteration to hide
// gather latency (round-4's 2-in-flight version was latency-exposed).
// ---------------------------------------------------------------------------
__global__ __launch_bounds__(192) void k_aggregate(const int* __restrict__ rp_r,
                                                   const int* __restrict__ el_r,
                                                   const int* __restrict__ si,
                                                   const float* __restrict__ x,
                                                   const float* __restrict__ v,
                                                   float* __restrict__ xout) {
    int node = blockIdx.x;
    int beg = rp_r[node], end = rp_r[node + 1];
    int tid = threadIdx.x;
    int b = node / NN;
    __shared__ int e_l[192];
    __shared__ int sb_l[192];
    const float4* v4 = (const float4*)v;
    const float4* x4 = (const float4*)x;
    float4 acc = {0.f, 0.f, 0.f, 0.f};
    for (int c = beg; c < end; c += 192) {
        int cnt = min(end - c, 192);
        if (tid < cnt) {
            int e = el_r[c + tid];
            e_l[tid] = e;
            sb_l[tid] = (b * NN + si[e]) * TD4;
        }
        __syncthreads();
        int i = 0;
        for (; i + 4 <= cnt; i += 4) {
            float4 v0 = v4[(size_t)e_l[i    ] * TD4 + tid];
            float4 x0 = x4[(size_t)sb_l[i   ] + tid];
            float4 v1 = v4[(size_t)e_l[i + 1] * TD4 + tid];
            float4 x1 = x4[(size_t)sb_l[i + 1] + tid];
            float4 v2 = v4[(size_t)e_l[i + 2] * TD4 + tid];
            float4 x2 = x4[(size_t)sb_l[i + 2] + tid];
            float4 v3 = v4[(size_t)e_l[i + 3] * TD4 + tid];
            float4 x3 = x4[(size_t)sb_l[i + 3] + tid];
            acc.x += v0.x * x0.x; acc.y += v0.y * x0.y; acc.z += v0.z * x0.z; acc.w += v0.w * x0.w;
            acc.x += v1.x * x1.x; acc.y += v1.y * x1.y; acc.z += v1.z * x1.z; acc.w += v1.w * x1.w;
            acc.x += v2.x * x2.x; acc.y += v2.y * x2.y; acc.z += v2.z * x2.z; acc.w += v2.w * x2.w;
            acc.x += v3.x * x3.x; acc.y += v3.y * x3.y; acc.z += v3.z * x3.z; acc.w += v3.w * x3.w;
        }
        for (; i < cnt; ++i) {
            float4 vv = v4[(size_t)e_l[i] * TD4 + tid];
            float4 xx = x4[(size_t)sb_l[i] + tid];
            acc.x += vv.x * xx.x; acc.y += vv.y * xx.y;
            acc.z += vv.z * xx.z; acc.w += vv.w * xx.w;
        }
        __syncthreads();
    }
    size_t nb = (size_t)node * TD4 + tid;
    float4 xv = x4[nb];
    float4 o;
    o.x = xv.x + STEPF * (acc.x - xv.x);
    o.y = xv.y + STEPF * (acc.y - xv.y);
    o.z = xv.z + STEPF * (acc.z - xv.z);
    o.w = xv.w + STEPF * (acc.w - xv.w);
    ((float4*)xout)[nb] = o;
}

// ---------------------------------------------------------------------------
extern "C" void kernel_launch(void* const* d_in, const int* in_sizes, int n_in,
                              void* d_out, int out_size, void* d_ws, size_t ws_size,
                              hipStream_t stream) {
    const float* x    = (const float*)d_in[0];
    const int*   bi   = (const int*)d_in[1];
    const int*   si   = (const int*)d_in[2];
    const int*   ri   = (const int*)d_in[3];
    const float* A1_w = (const float*)d_in[4];
    const float* A1_b = (const float*)d_in[5];
    const float* A2_w = (const float*)d_in[6];
    const float* A2_b = (const float*)d_in[7];
    const float* A3_w = (const float*)d_in[8];
    // d_in[9] = A3_b: cancels in z_ij - z_ji, unused
    const float* A4_w = (const float*)d_in[10];
    const float* A4_b = (const float*)d_in[11];

    float* xout = (float*)d_out;                          // [B,N,T,D]
    float* v    = (float*)d_out + (size_t)BN * TD;        // [E,T,D] final v_ij

    // Workspace: Q1,Q2 f16; frag-packed f16 weights; CSR ints (~25 MB)
    unsigned short* Q1  = (unsigned short*)d_ws;
    unsigned short* Q2  = Q1 + (size_t)ROWS * HIDN;
    unsigned short* W3f = Q2 + (size_t)ROWS * HIDN;       // 8192
    unsigned short* W4f = W3f + 8192;                     // 4096
    unsigned short* W1f = W4f + 4096;                     // 8192
    unsigned short* W2f = W1f + 8192;                     // 8192
    int* cnt_s = (int*)(W2f + 8192);
    int* cnt_r = cnt_s + BN;
    int* rp_s  = cnt_r + BN;
    int* rp_r  = rp_s + BN + 1;
    int* cur_s = rp_r + BN + 1;
    int* cur_r = cur_s + BN;
    int* el_s  = cur_r + BN;
    int* el_r  = el_s + EE;

    k_zero<<<(2 * BN + 255) / 256, 256, 0, stream>>>(cnt_s, 2 * BN);
    k_count<<<EE / 256, 256, 0, stream>>>(bi, si, ri, cnt_s, cnt_r);
    k_scan<<<2, 256, 0, stream>>>(cnt_s, cnt_r, rp_s, rp_r, cur_s, cur_r);
    k_fill<<<EE / 256, 256, 0, stream>>>(bi, si, ri, cur_s, cur_r, el_s, el_r);
    k_prep_w<<<112, 256, 0, stream>>>(A3_w, A4_w, A1_w, A2_w, W3f, W4f, W1f, W2f);
    k_node_proj<<<ROWS / 32, 256, 0, stream>>>(x, W1f, W2f, A1_b, A2_b, Q1, Q2);
    k_edge_seg<<<BN, 256, 0, stream>>>(Q1, Q2, ri, rp_s, el_s, W3f, W4f, A4_b, v);
    k_aggregate<<<BN, 192, 0, stream>>>(rp_r, el_r, si, x, v, xout);
}

// Round 6
// 438.265 us; speedup vs baseline: 1.1307x; 1.1307x over previous
//
#include <hip/hip_runtime.h>
#include <math.h>

// Problem constants (from reference)
#define BB 4
#define NN 1000
#define TT 12
#define DD 64
#define HIDN 128
#define EFN 64
#define EE 64000
#define BN (BB*NN)        // 4000 segments
#define ROWS (BN*TT)      // 48000 node-time rows
#define TD (TT*DD)        // 768 elements per edge/node row-block
#define TD4 (TD/4)        // 192 float4 per row-block
#define STEPF 0.1f
#define MAXSEG 22         // LDS-resident edges per sender segment (3 blocks/CU)
#define ELDS 40           // staged edge ids per block

typedef _Float16 f16x8 __attribute__((ext_vector_type(8)));   // 8 x f16 (4 VGPR)
typedef float f32x4 __attribute__((ext_vector_type(4)));      // MFMA acc

__device__ __forceinline__ unsigned short f2h(float x) {
    _Float16 h = (_Float16)x;                 // v_cvt_f16_f32 (RNE)
    return __builtin_bit_cast(unsigned short, h);
}
__device__ __forceinline__ float h2f(unsigned short u) {
    return (float)__builtin_bit_cast(_Float16, u);
}

// ---------------------------------------------------------------------------
// CSR build helpers
// ---------------------------------------------------------------------------
__global__ __launch_bounds__(256) void k_zero(int* __restrict__ p, int n) {
    int i = blockIdx.x * 256 + threadIdx.x;
    if (i < n) p[i] = 0;
}

__global__ __launch_bounds__(256) void k_count(const int* __restrict__ bi,
                                               const int* __restrict__ si,
                                               const int* __restrict__ ri,
                                               int* __restrict__ cnt_s,
                                               int* __restrict__ cnt_r) {
    int e = blockIdx.x * 256 + threadIdx.x;
    if (e < EE) {
        int b = bi[e];
        atomicAdd(&cnt_s[b * NN + si[e]], 1);
        atomicAdd(&cnt_r[b * NN + ri[e]], 1);
    }
}

__global__ __launch_bounds__(256) void k_scan(const int* __restrict__ cnt_s,
                                              const int* __restrict__ cnt_r,
                                              int* __restrict__ rp_s, int* __restrict__ rp_r,
                                              int* __restrict__ cur_s, int* __restrict__ cur_r) {
    const int* cnt = blockIdx.x ? cnt_r : cnt_s;
    int* rp  = blockIdx.x ? rp_r  : rp_s;
    int* cur = blockIdx.x ? cur_r : cur_s;
    __shared__ int part[256];
    int tid = threadIdx.x;
    const int chunk = 16;
    int bgn = tid * chunk;
    int end = min(bgn + chunk, BN);
    int s = 0;
    for (int i = bgn; i < end; ++i) s += cnt[i];
    part[tid] = s;
    __syncthreads();
    for (int off = 1; off < 256; off <<= 1) {
        int v = part[tid];
        if (tid >= off) v += part[tid - off];
        __syncthreads();
        part[tid] = v;
        __syncthreads();
    }
    int run = tid ? part[tid - 1] : 0;
    for (int i = bgn; i < end; ++i) { rp[i] = run; cur[i] = run; run += cnt[i]; }
    if (tid == 255) rp[BN] = part[255];
}

__global__ __launch_bounds__(256) void k_fill(const int* __restrict__ bi,
                                              const int* __restrict__ si,
                                              const int* __restrict__ ri,
                                              int* __restrict__ cur_s, int* __restrict__ cur_r,
                                              int* __restrict__ el_s, int* __restrict__ el_r) {
    int e = blockIdx.x * 256 + threadIdx.x;
    if (e < EE) {
        int b = bi[e];
        int ps = atomicAdd(&cur_s[b * NN + si[e]], 1);
        el_s[ps] = e;
        int pr = atomicAdd(&cur_r[b * NN + ri[e]], 1);
        el_r[pr] = e;
    }
}

// ---------------------------------------------------------------------------
// Weight prep: repack all four weight matrices into f16 MFMA B-fragment order
// for 16x16x32: frag[kt][nt][lane][j] = W[kt*32 + (lane>>4)*8 + j][nt*16 + (lane&15)]
//   W3f: A3_w [128,64]  (4 kt x 4 nt) -> 8192
//   W4f: A4_w [64,64]   (2 kt x 4 nt) -> 4096
//   W1f: A1_w [64,128]  (2 kt x 8 nt) -> 8192
//   W2f: A2_w [64,128]  (2 kt x 8 nt) -> 8192
// ---------------------------------------------------------------------------
__global__ __launch_bounds__(256) void k_prep_w(const float* __restrict__ A3_w,
                                                const float* __restrict__ A4_w,
                                                const float* __restrict__ A1_w,
                                                const float* __restrict__ A2_w,
                                                unsigned short* __restrict__ W3f,
                                                unsigned short* __restrict__ W4f,
                                                unsigned short* __restrict__ W1f,
                                                unsigned short* __restrict__ W2f) {
    int i = blockIdx.x * 256 + threadIdx.x;    // 0 .. 28671
    if (i < 8192) {
        int j = i & 7, lane = (i >> 3) & 63, nt = (i >> 9) & 3, kt = i >> 11;
        int k = kt * 32 + (lane >> 4) * 8 + j;
        int n = nt * 16 + (lane & 15);
        W3f[i] = f2h(A3_w[k * 64 + n]);
    } else if (i < 12288) {
        int ii = i - 8192;
        int j = ii & 7, lane = (ii >> 3) & 63, nt = (ii >> 9) & 3, kt = ii >> 11;
        int k = kt * 32 + (lane >> 4) * 8 + j;
        int n = nt * 16 + (lane & 15);
        W4f[ii] = f2h(A4_w[k * 64 + n]);
    } else if (i < 20480) {
        int ii = i - 12288;
        int j = ii & 7, lane = (ii >> 3) & 63, nt = (ii >> 9) & 7, kt = ii >> 12;
        int k = kt * 32 + (lane >> 4) * 8 + j;
        int n = nt * 16 + (lane & 15);
        W1f[ii] = f2h(A1_w[k * 128 + n]);
    } else {
        int ii = i - 20480;
        int j = ii & 7, lane = (ii >> 3) & 63, nt = (ii >> 9) & 7, kt = ii >> 12;
        int k = kt * 32 + (lane >> 4) * 8 + j;
        int n = nt * 16 + (lane & 15);
        W2f[ii] = f2h(A2_w[k * 128 + n]);
    }
}

// ---------------------------------------------------------------------------
// K1 (MFMA): Q1 = x@A1_w + A1_b, Q2 = x@A2_w + A2_b -> f16.
// [48000,64]@[64,128]: each wave does a 16-row x 128-col tile with 16 MFMAs.
// ---------------------------------------------------------------------------
__global__ __launch_bounds__(256) void k_node_proj(const float* __restrict__ x,
                                                   const unsigned short* __restrict__ W1f,
                                                   const unsigned short* __restrict__ W2f,
                                                   const float* __restrict__ A1_b,
                                                   const float* __restrict__ A2_b,
                                                   unsigned short* __restrict__ Q1,
                                                   unsigned short* __restrict__ Q2) {
    int tid  = threadIdx.x;
    int lane = tid & 63;
    int wvv  = tid >> 6;            // 0..3
    int mat  = wvv >> 1;            // 0 -> Q1, 1 -> Q2
    int rt   = blockIdx.x * 32 + (wvv & 1) * 16;
    int quad = lane >> 4;
    int m    = lane & 15;

    const unsigned short* Wf = mat ? W2f : W1f;
    const float* bias = mat ? A2_b : A1_b;
    unsigned short* Qo = mat ? Q2 : Q1;

    f16x8 wf[2][8];
#pragma unroll
    for (int kt = 0; kt < 2; ++kt)
#pragma unroll
        for (int nt = 0; nt < 8; ++nt)
            wf[kt][nt] = *(const f16x8*)(const void*)&Wf[((kt * 8 + nt) * 64 + lane) * 8];

    float bb[8];
#pragma unroll
    for (int nt = 0; nt < 8; ++nt) bb[nt] = bias[nt * 16 + m];

    // A fragments: af[kt][j] = x[rt+m][kt*32 + quad*8 + j], f32 -> f16
    const float* xr = x + (size_t)(rt + m) * 64;
    f16x8 af[2];
#pragma unroll
    for (int kt = 0; kt < 2; ++kt) {
        float4 u0 = *(const float4*)(xr + kt * 32 + (lane >> 4) * 8);
        float4 u1 = *(const float4*)(xr + kt * 32 + (lane >> 4) * 8 + 4);
        f16x8 a;
        a[0] = (_Float16)u0.x; a[1] = (_Float16)u0.y; a[2] = (_Float16)u0.z; a[3] = (_Float16)u0.w;
        a[4] = (_Float16)u1.x; a[5] = (_Float16)u1.y; a[6] = (_Float16)u1.z; a[7] = (_Float16)u1.w;
        af[kt] = a;
    }

    f32x4 acc[8];
#pragma unroll
    for (int nt = 0; nt < 8; ++nt) {
        f32x4 o = (f32x4){0.f, 0.f, 0.f, 0.f};
        o = __builtin_amdgcn_mfma_f32_16x16x32_f16(af[0], wf[0][nt], o, 0, 0, 0);
        o = __builtin_amdgcn_mfma_f32_16x16x32_f16(af[1], wf[1][nt], o, 0, 0, 0);
        acc[nt] = o;
    }
#pragma unroll
    for (int nt = 0; nt < 8; ++nt)
#pragma unroll
        for (int r = 0; r < 4; ++r)
            Qo[(size_t)(rt + quad * 4 + r) * 128 + nt * 16 + m] = f2h(acc[nt][r] + bb[nt]);
}

// ---------------------------------------------------------------------------
// K2 (f16 MFMA + fused segment softmax): one workgroup per sender segment.
//  - Single-edge loop (round-5's 2-edge ILP raised VGPR 104->140, halved
//    occupancy, +62 us: TLP is the latency-hiding currency here, not ILP).
//  - NO occupancy hints (rounds 1/3: hints -> 84-reg spill collapse).
//  - MAXSEG 22 -> LDS 51.5 KB -> 3 blocks/CU (12 waves): occupancy probe now
//    that the allocator is healthy (rounds 1-3's high FETCH at 3 blocks is
//    fully explained by spill traffic; this isolates the variable).
// ---------------------------------------------------------------------------
__global__ __launch_bounds__(256)
void k_edge_seg(const unsigned short* __restrict__ Q1,
                const unsigned short* __restrict__ Q2,
                const int* __restrict__ ri,
                const int* __restrict__ rp_s,
                const int* __restrict__ el_s,
                const unsigned short* __restrict__ W3f,
                const unsigned short* __restrict__ W4f,
                const float* __restrict__ A4_b,
                float* __restrict__ v) {
    __shared__ unsigned short Vseg[MAXSEG][12][64];   // 33792 B, XOR-swizzled cols
    __shared__ __align__(16) _Float16 Hs[4][16][72];  // 9216 B (pitch 72: 16B-aligned b128 rows)
    __shared__ __align__(16) _Float16 W4s[4096];      // 8192 B, frag-packed A4 weights
    __shared__ int e_lds[ELDS];
    __shared__ int rn_lds[ELDS];

    int seg = blockIdx.x;
    int beg = rp_s[seg], end = rp_s[seg + 1];
    int S = end - beg;
    if (S == 0) return;

    int tid  = threadIdx.x;
    int lane = tid & 63;
    int wv   = tid >> 6;
    int quad = lane >> 4;
    int m    = lane & 15;
    int kbase = quad * 8;
    int b    = seg / NN;           // batch id (seg = b*NN + sender)

    // ---- block-start staging ----
    for (int i = tid; i < 512; i += 256)
        *(f16x8*)&W4s[i * 8] = *(const f16x8*)(const void*)&W4f[i * 8];
    if (tid < ELDS && tid < S) {
        int e = el_s[beg + tid];
        e_lds[tid] = e;
        rn_lds[tid] = b * NN + ri[e];
    }

    // w3 resident in registers (64 VGPR)
    f16x8 w3[4][4];
#pragma unroll
    for (int kt = 0; kt < 4; ++kt)
#pragma unroll
        for (int nt = 0; nt < 4; ++nt)
            w3[kt][nt] = *(const f16x8*)(const void*)&W3f[((kt * 4 + nt) * 64 + lane) * 8];
    float b4[4];
#pragma unroll
    for (int nt = 0; nt < 4; ++nt) b4[nt] = A4_b[nt * 16 + m];

    const f16x8 hz = {0, 0, 0, 0, 0, 0, 0, 0};

    // sender fragments: loop-invariant, persistent in regs (32 VGPR)
    f16x8 s1[4], s2[4];
    if (m < 12) {
        const unsigned short* p1 = Q1 + (size_t)seg * (TT * HIDN) + m * 128 + kbase;
        const unsigned short* p2 = Q2 + (size_t)seg * (TT * HIDN) + m * 128 + kbase;
#pragma unroll
        for (int kt = 0; kt < 4; ++kt) {
            s1[kt] = *(const f16x8*)(const void*)(p1 + kt * 32);
            s2[kt] = *(const f16x8*)(const void*)(p2 + kt * 32);
        }
    } else {
#pragma unroll
        for (int kt = 0; kt < 4; ++kt) { s1[kt] = hz; s2[kt] = hz; }
    }

    __syncthreads();

    // ---- compute v_pre for this segment's edges, one edge per wave-iter ----
    for (int li = wv; li < S; li += 4) {
        int e, rn;
        if (li < ELDS) { e = e_lds[li]; rn = rn_lds[li]; }
        else           { e = el_s[beg + li]; rn = b * NN + ri[e]; }

        const unsigned short* pr1 = Q1 + (size_t)rn * (TT * HIDN) + m * 128 + kbase;
        const unsigned short* pr2 = Q2 + (size_t)rn * (TT * HIDN) + m * 128 + kbase;

        // Stage A3: Z = G @ A3 (K=128), per-kt load->consume keeps pressure low
        f32x4 acc[4];
#pragma unroll
        for (int nt = 0; nt < 4; ++nt) acc[nt] = (f32x4){0.f, 0.f, 0.f, 0.f};
#pragma unroll
        for (int kt = 0; kt < 4; ++kt) {
            f16x8 g;
            if (m < 12) {
                f16x8 r1 = *(const f16x8*)(const void*)(pr1 + kt * 32);
                f16x8 r2 = *(const f16x8*)(const void*)(pr2 + kt * 32);
                f16x8 a = s1[kt] + r2;                    // v_pk_add_f16
                f16x8 c = r1 + s2[kt];
                g = __builtin_elementwise_max(a, hz)      // v_pk_max_f16
                  - __builtin_elementwise_max(c, hz);
            } else {
                g = hz;
            }
#pragma unroll
            for (int nt = 0; nt < 4; ++nt)
                acc[nt] = __builtin_amdgcn_mfma_f32_16x16x32_f16(g, w3[kt][nt], acc[nt], 0, 0, 0);
        }

        // relu -> wave-private f16 LDS tile (C layout in, A layout out)
#pragma unroll
        for (int nt = 0; nt < 4; ++nt)
#pragma unroll
            for (int r = 0; r < 4; ++r)
                Hs[wv][quad * 4 + r][nt * 16 + m] = (_Float16)fmaxf(acc[nt][r], 0.f);

        const _Float16* hp = &Hs[wv][m][kbase];
        f16x8 hf0 = *(const f16x8*)hp;            // ds_read_b128: 8 f16 = A-frag
        f16x8 hf1 = *(const f16x8*)(hp + 32);

        // Stage A4: v_pre = H @ A4 + b4 (K=64), w4 fragments from LDS
#pragma unroll
        for (int nt = 0; nt < 4; ++nt) {
            f32x4 o = (f32x4){b4[nt], b4[nt], b4[nt], b4[nt]};
            o = __builtin_amdgcn_mfma_f32_16x16x32_f16(hf0, *(const f16x8*)&W4s[(nt * 64 + lane) * 8], o, 0, 0, 0);
            o = __builtin_amdgcn_mfma_f32_16x16x32_f16(hf1, *(const f16x8*)&W4s[((4 + nt) * 64 + lane) * 8], o, 0, 0, 0);
            if (quad < 3) {
                if (li < MAXSEG) {
                    int cc = ((nt ^ quad) << 4) | m;      // swizzled column
#pragma unroll
                    for (int r = 0; r < 4; ++r)
                        Vseg[li][quad * 4 + r][cc] = f2h(o[r]);
                } else {            // rare overflow: spill fp32 v_pre to global
                    size_t ebase = (size_t)e * TD;
#pragma unroll
                    for (int r = 0; r < 4; ++r)
                        v[ebase + (quad * 4 + r) * 64 + nt * 16 + m] = o[r];
                }
            }
        }
    }
    __syncthreads();

    // ---- fused segment softmax: thread owns j = tid, tid+256, tid+512 ----
    int d  = tid & 63;
    int tb = tid >> 6;          // row for jj is tb + 4*jj; row>>2 == jj (tb<4)
    int nL = min(S, MAXSEG);
    int dd[3];
#pragma unroll
    for (int jj = 0; jj < 3; ++jj) dd[jj] = d ^ (jj << 4);   // un-swizzle

    float mj[3] = {-1e30f, -1e30f, -1e30f};
    for (int i = 0; i < nL; ++i) {
#pragma unroll
        for (int jj = 0; jj < 3; ++jj)
            mj[jj] = fmaxf(mj[jj], h2f(Vseg[i][tb + 4 * jj][dd[jj]]));
    }
    for (int i = MAXSEG; i < S; ++i) {
        int e = (i < ELDS) ? e_lds[i] : el_s[beg + i];
        size_t ebase = (size_t)e * TD;
#pragma unroll
        for (int jj = 0; jj < 3; ++jj)
            mj[jj] = fmaxf(mj[jj], v[ebase + (tb + 4 * jj) * 64 + d]);
    }

    float sj[3] = {0.f, 0.f, 0.f};
    for (int i = 0; i < nL; ++i) {
#pragma unroll
        for (int jj = 0; jj < 3; ++jj)
            sj[jj] += __expf(h2f(Vseg[i][tb + 4 * jj][dd[jj]]) - mj[jj]);
    }
    for (int i = MAXSEG; i < S; ++i) {
        int e = (i < ELDS) ? e_lds[i] : el_s[beg + i];
        size_t ebase = (size_t)e * TD;
#pragma unroll
        for (int jj = 0; jj < 3; ++jj)
            sj[jj] += __expf(v[ebase + (tb + 4 * jj) * 64 + d] - mj[jj]);
    }

    float inv[3];
#pragma unroll
    for (int jj = 0; jj < 3; ++jj) inv[jj] = 1.f / (sj[jj] + 1e-12f);

    for (int i = 0; i < nL; ++i) {
        int e = (i < ELDS) ? e_lds[i] : el_s[beg + i];
        size_t ebase = (size_t)e * TD;
#pragma unroll
        for (int jj = 0; jj < 3; ++jj)
            v[ebase + (tb + 4 * jj) * 64 + d] =
                __expf(h2f(Vseg[i][tb + 4 * jj][dd[jj]]) - mj[jj]) * inv[jj];
    }
    for (int i = MAXSEG; i < S; ++i) {
        int e = (i < ELDS) ? e_lds[i] : el_s[beg + i];
        size_t ebase = (size_t)e * TD;
#pragma unroll
        for (int jj = 0; jj < 3; ++jj) {
            size_t a = ebase + (tb + 4 * jj) * 64 + d;
            v[a] = __expf(v[a] - mj[jj]) * inv[jj];
        }
    }
}

// ---------------------------------------------------------------------------
// K4: per-node inbound aggregation + state update. 192 threads x float4,
// edge loop unrolled x4 (8 independent loads in flight).
// ---------------------------------------------------------------------------
__global__ __launch_bounds__(192) void k_aggregate(const int* __restrict__ rp_r,
                                                   const int* __restrict__ el_r,
                                                   const int* __restrict__ si,
                                                   const float* __restrict__ x,
                                                   const float* __restrict__ v,
                                                   float* __restrict__ xout) {
    int node = blockIdx.x;
    int beg = rp_r[node], end = rp_r[node + 1];
    int tid = threadIdx.x;
    int b = node / NN;
    __shared__ int e_l[192];
    __shared__ int sb_l[192];
    const float4* v4 = (const float4*)v;
    const float4* x4 = (const float4*)x;
    float4 acc = {0.f, 0.f, 0.f, 0.f};
    for (int c = beg; c < end; c += 192) {
        int cnt = min(end - c, 192);
        if (tid < cnt) {
            int e = el_r[c + tid];
            e_l[tid] = e;
            sb_l[tid] = (b * NN + si[e]) * TD4;
        }
        __syncthreads();
        int i = 0;
        for (; i + 4 <= cnt; i += 4) {
            float4 v0 = v4[(size_t)e_l[i    ] * TD4 + tid];
            float4 x0 = x4[(size_t)sb_l[i   ] + tid];
            float4 v1 = v4[(size_t)e_l[i + 1] * TD4 + tid];
            float4 x1 = x4[(size_t)sb_l[i + 1] + tid];
            float4 v2 = v4[(size_t)e_l[i + 2] * TD4 + tid];
            float4 x2 = x4[(size_t)sb_l[i + 2] + tid];
            float4 v3 = v4[(size_t)e_l[i + 3] * TD4 + tid];
            float4 x3 = x4[(size_t)sb_l[i + 3] + tid];
            acc.x += v0.x * x0.x; acc.y += v0.y * x0.y; acc.z += v0.z * x0.z; acc.w += v0.w * x0.w;
            acc.x += v1.x * x1.x; acc.y += v1.y * x1.y; acc.z += v1.z * x1.z; acc.w += v1.w * x1.w;
            acc.x += v2.x * x2.x; acc.y += v2.y * x2.y; acc.z += v2.z * x2.z; acc.w += v2.w * x2.w;
            acc.x += v3.x * x3.x; acc.y += v3.y * x3.y; acc.z += v3.z * x3.z; acc.w += v3.w * x3.w;
        }
        for (; i < cnt; ++i) {
            float4 vv = v4[(size_t)e_l[i] * TD4 + tid];
            float4 xx = x4[(size_t)sb_l[i] + tid];
            acc.x += vv.x * xx.x; acc.y += vv.y * xx.y;
            acc.z += vv.z * xx.z; acc.w += vv.w * xx.w;
        }
        __syncthreads();
    }
    size_t nb = (size_t)node * TD4 + tid;
    float4 xv = x4[nb];
    float4 o;
    o.x = xv.x + STEPF * (acc.x - xv.x);
    o.y = xv.y + STEPF * (acc.y - xv.y);
    o.z = xv.z + STEPF * (acc.z - xv.z);
    o.w = xv.w + STEPF * (acc.w - xv.w);
    ((float4*)xout)[nb] = o;
}

// ---------------------------------------------------------------------------
extern "C" void kernel_launch(void* const* d_in, const int* in_sizes, int n_in,
                              void* d_out, int out_size, void* d_ws, size_t ws_size,
                              hipStream_t stream) {
    const float* x    = (const float*)d_in[0];
    const int*   bi   = (const int*)d_in[1];
    const int*   si   = (const int*)d_in[2];
    const int*   ri   = (const int*)d_in[3];
    const float* A1_w = (const float*)d_in[4];
    const float* A1_b = (const float*)d_in[5];
    const float* A2_w = (const float*)d_in[6];
    const float* A2_b = (const float*)d_in[7];
    const float* A3_w = (const float*)d_in[8];
    // d_in[9] = A3_b: cancels in z_ij - z_ji, unused
    const float* A4_w = (const float*)d_in[10];
    const float* A4_b = (const float*)d_in[11];

    float* xout = (float*)d_out;                          // [B,N,T,D]
    float* v    = (float*)d_out + (size_t)BN * TD;        // [E,T,D] final v_ij

    // Workspace: Q1,Q2 f16; frag-packed f16 weights; CSR ints (~25 MB)
    unsigned short* Q1  = (unsigned short*)d_ws;
    unsigned short* Q2  = Q1 + (size_t)ROWS * HIDN;
    unsigned short* W3f = Q2 + (size_t)ROWS * HIDN;       // 8192
    unsigned short* W4f = W3f + 8192;                     // 4096
    unsigned short* W1f = W4f + 4096;                     // 8192
    unsigned short* W2f = W1f + 8192;                     // 8192
    int* cnt_s = (int*)(W2f + 8192);
    int* cnt_r = cnt_s + BN;
    int* rp_s  = cnt_r + BN;
    int* rp_r  = rp_s + BN + 1;
    int* cur_s = rp_r + BN + 1;
    int* cur_r = cur_s + BN;
    int* el_s  = cur_r + BN;
    int* el_r  = el_s + EE;

    k_zero<<<(2 * BN + 255) / 256, 256, 0, stream>>>(cnt_s, 2 * BN);
    k_count<<<EE / 256, 256, 0, stream>>>(bi, si, ri, cnt_s, cnt_r);
    k_scan<<<2, 256, 0, stream>>>(cnt_s, cnt_r, rp_s, rp_r, cur_s, cur_r);
    k_fill<<<EE / 256, 256, 0, stream>>>(bi, si, ri, cur_s, cur_r, el_s, el_r);
    k_prep_w<<<112, 256, 0, stream>>>(A3_w, A4_w, A1_w, A2_w, W3f, W4f, W1f, W2f);
    k_node_proj<<<ROWS / 32, 256, 0, stream>>>(x, W1f, W2f, A1_b, A2_b, Q1, Q2);
    k_edge_seg<<<BN, 256, 0, stream>>>(Q1, Q2, ri, rp_s, el_s, W3f, W4f, A4_b, v);
    k_aggregate<<<BN, 192, 0, stream>>>(rp_r, el_r, si, x, v, xout);
}